// Round 5
// baseline (445.012 us; speedup 1.0000x reference)
//
#include <hip/hip_runtime.h>
#include <math.h>

// ViT Vector Quantizer: z [32,1024,32] f32, embedding [8192,32] f32.
// Outputs (concat, read as f32): z_q_out [N*D], loss [1], idx [N] (as floats).
//
// R11: occupancy + launch-count round.
//   - k_argmin_mfma: 128-code chunks (2x16KB LDS dbuf) + __launch_bounds__(256,4)
//     -> 4 blocks/CU (was 2 at 64KB). m114: resident blocks overlap each
//     other's barrier/DMA drains -> MfmaUtil 46% -> ~60%+.
//   - k_cleanup is FUSED into k_rescore: flagged rows are resolved in-block by
//     a full exact 8192-code scan (4 waves x 32 codes/lane), per-code fp32
//     score bitwise-identical to the old k_cleanup (same -en_h + float4 fma
//     order), same packed-u64 max/tie->min-k. mp2/list/cnt machinery deleted;
//     one fewer launch (theory: ~15us fixed cost per launch).
//   K0 k_prep -> K1 k_argmin_mfma -> K1b k_merge -> K2 k_rescore -> K3 k_epi.

#define D 32
#define KCODES 8192
#define CH 128             // codes per chunk (argmin staging + rescore unit)
#define NCHUNK (KCODES / CH)       // 64
#define MARGIN 2.5e-4f     // ~20x worst-case split-bf16 error bound
#define EPS 1e-12f

typedef short bf16x8 __attribute__((ext_vector_type(8)));
typedef unsigned short u16x8 __attribute__((ext_vector_type(8)));
typedef float f32x4 __attribute__((ext_vector_type(4)));

static __device__ __forceinline__ unsigned short f2bf(float x) {  // RNE bf16 bits
  unsigned u = __float_as_uint(x);
  return (unsigned short)((u + 0x7FFFu + ((u >> 16) & 1u)) >> 16);
}
static __device__ __forceinline__ float bf2f(unsigned short s) {
  return __uint_as_float(((unsigned)s) << 16);
}
static __device__ __forceinline__ void gload_lds16(const void* g, void* l) {
  __builtin_amdgcn_global_load_lds(
      (const __attribute__((address_space(1))) void*)g,
      (__attribute__((address_space(3))) void*)l, 16, 0, 0);
}

// MFMA fragment layouts (validated in prior rounds; A and B mappings are
// identical index formulas, so the same swizzled data serves either operand):
//   A[m][k]: m = lane&15, k = (lane>>4)*8 + j   (8 bf16/lane, contiguous 16B)
//   B[k][n]: n = lane&15, k = (lane>>4)*8 + j
//   C[m][n]: n = lane&15, m = (lane>>4)*4 + reg

__global__ __launch_bounds__(256) void k_prep(const float* __restrict__ z,
                                              const float* __restrict__ emb,
                                              float* __restrict__ en,
                                              float* __restrict__ en_h,
                                              unsigned short* __restrict__ eswz,
                                              unsigned short* __restrict__ zswz_hi,
                                              unsigned short* __restrict__ zswz_lo,
                                              float* __restrict__ zn,
                                              float* __restrict__ loss,
                                              int N) {
  int v = blockIdx.x * 256 + threadIdx.x;
  if (v == 0) *loss = 0.f;
  if (v >= KCODES + N) return;
  const float* src = (v < KCODES) ? (emb + (size_t)v * D) : (z + (size_t)(v - KCODES) * D);

  float x[D];
  const float4* p = reinterpret_cast<const float4*>(src);
#pragma unroll
  for (int j = 0; j < D / 4; ++j) {
    float4 q = p[j];
    x[4 * j + 0] = q.x; x[4 * j + 1] = q.y; x[4 * j + 2] = q.z; x[4 * j + 3] = q.w;
  }
  float ss = 0.f;
#pragma unroll
  for (int j = 0; j < D; ++j) ss = fmaf(x[j], x[j], ss);
  float n = fmaxf(sqrtf(ss), EPS);
#pragma unroll
  for (int j = 0; j < D; ++j) x[j] = x[j] / n;   // true division mirrors reference

  unsigned short hi[D], lo[D];
#pragma unroll
  for (int j = 0; j < D; ++j) {
    hi[j] = f2bf(x[j]);
    lo[j] = f2bf(x[j] - bf2f(hi[j]));   // x - bf16(x) exact in fp32
  }

  if (v < KCODES) {
    float4* o = reinterpret_cast<float4*>(en + (size_t)v * D);
    float s2 = 0.f;
#pragma unroll
    for (int j = 0; j < D / 4; ++j) {
      float4 q = {x[4 * j], x[4 * j + 1], x[4 * j + 2], x[4 * j + 3]};
      s2 = fmaf(q.x, q.x, fmaf(q.y, q.y, fmaf(q.z, q.z, fmaf(q.w, q.w, s2))));
      o[j] = q;
    }
    en_h[v] = 0.5f * s2;
    int tl = v >> 4, m = v & 15;    // fragment swizzle (tile-of-16 codes)
#pragma unroll
    for (int q = 0; q < 4; ++q) {
      u16x8 hv, lv;
#pragma unroll
      for (int j = 0; j < 8; ++j) { hv[j] = hi[8 * q + j]; lv[j] = lo[8 * q + j]; }
      *(u16x8*)(eswz + (size_t)tl * 1024 + (q * 16 + m) * 8) = hv;
      *(u16x8*)(eswz + (size_t)tl * 1024 + 512 + (q * 16 + m) * 8) = lv;
    }
  } else {
    int r = v - KCODES;
    float4* zo = reinterpret_cast<float4*>(zn + (size_t)r * D);
#pragma unroll
    for (int j = 0; j < D / 4; ++j) {   // bitwise-exact normalized z for rescore
      float4 q = {x[4 * j], x[4 * j + 1], x[4 * j + 2], x[4 * j + 3]};
      zo[j] = q;
    }
    int g = r >> 4, m = r & 15;     // fragment swizzle (group-of-16 rows)
#pragma unroll
    for (int q = 0; q < 4; ++q) {
      u16x8 hv, lv;
#pragma unroll
      for (int j = 0; j < 8; ++j) { hv[j] = hi[8 * q + j]; lv[j] = lo[8 * q + j]; }
      *(u16x8*)(zswz_hi + (size_t)g * 512 + (q * 16 + m) * 8) = hv;
      *(u16x8*)(zswz_lo + (size_t)g * 512 + (q * 16 + m) * 8) = lv;
    }
  }
}

// Deferred-argmax MFMA pass. Grid = (N/256) row-sets x 4 code-quarters.
// Block = 4 waves; each wave holds z-fragments for 4 row-groups (64 rows) so
// one A-fragment (codes) LDS read feeds 12 MFMAs. 128-code chunks double-
// buffered in 2x16KB LDS -> 4 blocks/CU for barrier-drain overlap (m114).
__global__ __launch_bounds__(256, 4) void k_argmin_mfma(
    const unsigned short* __restrict__ zswz_hi,
    const unsigned short* __restrict__ zswz_lo,
    const unsigned short* __restrict__ eswz,
    float* __restrict__ res_s1, int* __restrict__ res_cb,
    float* __restrict__ res_s2) {
  __shared__ unsigned short lds_sh[2][8192];    // 2 x 16 KB double buffer

  const int tid = threadIdx.x;
  const int wid = tid >> 6, lane = tid & 63;
  const int lane15 = lane & 15, quad = lane >> 4;
  const int rs = blockIdx.x >> 2;               // row-set (256 rows)
  const int qt = blockIdx.x & 3;                // code quarter (16 chunks)

  bf16x8 zhi[4], zlo[4];
#pragma unroll
  for (int rg = 0; rg < 4; ++rg) {
    int g = rs * 16 + wid * 4 + rg;
    zhi[rg] = *(const bf16x8*)(zswz_hi + (size_t)g * 512 + lane * 8);
    zlo[rg] = *(const bf16x8*)(zswz_lo + (size_t)g * 512 + lane * 8);
  }

  float cm[4], s1g[4], s2c[4];
  int cb[4];
#pragma unroll
  for (int rg = 0; rg < 4; ++rg) {
    cm[rg] = -3.4e38f; s1g[rg] = -3.4e38f; s2c[rg] = -3.4e38f; cb[rg] = 0;
  }
  const f32x4 zero4 = {0.f, 0.f, 0.f, 0.f};

  // chunk = 128 codes = 8 tiles = 16 KB = 1024 float4; 4 x 16B per thread
  const float4* gall = reinterpret_cast<const float4*>(eswz) + (size_t)qt * 16 * 1024;
#pragma unroll
  for (int i = 0; i < 4; ++i) {   // stage chunk 0 into buf 0
    int off = i * 256 + tid;      // wave-uniform base + lane-contiguous (m104)
    gload_lds16(gall + off, (char*)&lds_sh[0][0] + (size_t)off * 16);
  }

  for (int c = 0; c < 16; ++c) {
    __syncthreads();              // drains vmcnt -> buffer c&1 fully staged
    if (c + 1 < 16) {             // next DMA overlaps this chunk's compute
      const float4* gn = gall + (size_t)(c + 1) * 1024;
      char* dst = (char*)&lds_sh[(c + 1) & 1][0];
#pragma unroll
      for (int i = 0; i < 4; ++i) {
        int off = i * 256 + tid;
        gload_lds16(gn + off, dst + (size_t)off * 16);
      }
    }
    const unsigned short* buf = &lds_sh[c & 1][0];
#pragma unroll
    for (int t = 0; t < 8; ++t) {
      bf16x8 ahi = *(const bf16x8*)(buf + t * 1024 + lane * 8);
      bf16x8 alo = *(const bf16x8*)(buf + t * 1024 + 512 + lane * 8);
#pragma unroll
      for (int rg = 0; rg < 4; ++rg) {
        // A = codes, B = z: C[m][n] -> n=lane15 = row-in-group, m = code
        f32x4 acc = __builtin_amdgcn_mfma_f32_16x16x32_bf16(ahi, zhi[rg], zero4, 0, 0, 0);
        acc = __builtin_amdgcn_mfma_f32_16x16x32_bf16(ahi, zlo[rg], acc, 0, 0, 0);
        acc = __builtin_amdgcn_mfma_f32_16x16x32_bf16(alo, zhi[rg], acc, 0, 0, 0);
        cm[rg] = fmaxf(cm[rg],
                       fmaxf(fmaxf(acc[0], acc[1]), fmaxf(acc[2], acc[3])));
      }
    }
    // chunk end: fold chunk max into (s1, best chunk, 2nd-best-partial-max)
#pragma unroll
    for (int rg = 0; rg < 4; ++rg) {
      float old1 = s1g[rg];
      s2c[rg] = fmaxf(s2c[rg], fminf(cm[rg], old1));
      bool better = cm[rg] > old1;                // strict: earlier chunk on tie
      cb[rg] = better ? (qt * 16 + c) : cb[rg];
      s1g[rg] = better ? cm[rg] : old1;
      cm[rg] = -3.4e38f;
    }
  }

  // merge the 4 quads (disjoint code subsets of same rows): xor 16 then 32
#pragma unroll
  for (int m = 16; m <= 32; m <<= 1) {
#pragma unroll
    for (int rg = 0; rg < 4; ++rg) {
      float o1 = __shfl_xor(s1g[rg], m, 64);
      float o2 = __shfl_xor(s2c[rg], m, 64);
      int ob = __shfl_xor(cb[rg], m, 64);
      s2c[rg] = fmaxf(fmaxf(s2c[rg], o2), fminf(s1g[rg], o1));
      bool better = o1 > s1g[rg];
      s1g[rg] = better ? o1 : s1g[rg];
      cb[rg] = better ? ob : cb[rg];
    }
  }
  if (quad == 0) {
#pragma unroll
    for (int rg = 0; rg < 4; ++rg) {
      int row = rs * 256 + wid * 64 + rg * 16 + lane15;
      res_s1[(size_t)row * 4 + qt] = s1g[rg];
      res_cb[(size_t)row * 4 + qt] = cb[rg];
      res_s2[(size_t)row * 4 + qt] = s2c[rg];
    }
  }
}

// Per-row merge of the 4 code-quarter results. float4/int4 coalesced.
__global__ __launch_bounds__(256) void k_merge(const float* __restrict__ res_s1,
                                               const int* __restrict__ res_cb,
                                               const float* __restrict__ res_s2,
                                               int* __restrict__ row_cb,
                                               float* __restrict__ row_s2) {
  int row = blockIdx.x * 256 + threadIdx.x;
  float4 s1q = reinterpret_cast<const float4*>(res_s1)[row];
  float4 s2q = reinterpret_cast<const float4*>(res_s2)[row];
  int4 cbq = reinterpret_cast<const int4*>(res_cb)[row];
  float s1b = s1q.x;  int cbb = cbq.x;  float s2b = s2q.x;
  {
    float s1p = s1q.y, s2p = s2q.y; int cbp = cbq.y;
    s2b = fmaxf(fmaxf(s2b, s2p), fminf(s1b, s1p));
    bool better = s1p > s1b;  s1b = better ? s1p : s1b;  cbb = better ? cbp : cbb;
  }
  {
    float s1p = s1q.z, s2p = s2q.z; int cbp = cbq.z;
    s2b = fmaxf(fmaxf(s2b, s2p), fminf(s1b, s1p));
    bool better = s1p > s1b;  s1b = better ? s1p : s1b;  cbb = better ? cbp : cbb;
  }
  {
    float s1p = s1q.w, s2p = s2q.w; int cbp = cbq.w;
    s2b = fmaxf(fmaxf(s2b, s2p), fminf(s1b, s1p));
    bool better = s1p > s1b;  s1b = better ? s1p : s1b;  cbb = better ? cbp : cbb;
  }
  row_cb[row] = cbb;
  row_s2[row] = s2b;
}

// Exact fp32 rescore of each row's winning 128-code chunk + INLINE exact
// full-scan for ambiguous rows (replaces k_cleanup; no extra launch).
// Grid = 64 chunks x 8 row-ranges. Block stages its chunk (fp32, padded
// stride 36), scans its 4096-row range (4 B/row), collects matching rows,
// then row-per-wave: 2 codes/lane, packed u64 wave argmax (max s, tie ->
// min k). Flag test: row_s2 (raw approx dot) vs dotw = sC + en_h[kC].
// Flagged rows go to an LDS list; after the main loop the whole block does
// an exact 8192-code global-read scan per flagged row (bitwise-identical
// per-code score to the old k_cleanup).
__global__ __launch_bounds__(256) void k_rescore(
    const float* __restrict__ zn, const float* __restrict__ en,
    const float* __restrict__ en_h,
    const int* __restrict__ row_cb, const float* __restrict__ row_s2,
    int* __restrict__ idx_ws, int N) {
  __shared__ float en_s[CH * 36];      // [code][36] padded, 16B-aligned rows
  __shared__ float enh_s[CH];
  __shared__ unsigned short rows_s[4096];
  __shared__ unsigned short flg_s[4096];
  __shared__ unsigned long long wred[4];
  __shared__ int nmatch, nflag;

  const int tid = threadIdx.x;
  const int c = blockIdx.x >> 3;       // chunk 0..63
  const int sb = blockIdx.x & 7;       // row sub-range
  const int rows_per = N >> 3;         // 4096
  const int r0 = sb * rows_per;

  if (tid == 0) { nmatch = 0; nflag = 0; }
  // stage chunk: 1024 float4 of en -> padded LDS
  const float4* e4 = reinterpret_cast<const float4*>(en) + (size_t)c * (CH * 8);
#pragma unroll
  for (int i = 0; i < 4; ++i) {
    int idx = i * 256 + tid;
    float4 v4 = e4[idx];
    int code = idx >> 3, j = idx & 7;
    *reinterpret_cast<float4*>(&en_s[code * 36 + j * 4]) = v4;
  }
  if (tid < CH) enh_s[tid] = en_h[c * CH + tid];
  __syncthreads();

  // scan rows: collect rows whose (pre-merged) best chunk == c
  for (int i = 0; i < rows_per / 256; ++i) {
    int rrel = i * 256 + tid;
    if (row_cb[r0 + rrel] == c) {
      int pos = atomicAdd(&nmatch, 1);
      rows_s[pos] = (unsigned short)rrel;
    }
  }
  __syncthreads();
  const int nm = nmatch;
  const int lane = tid & 63, wid = tid >> 6;

  for (int ri = wid; ri < nm; ri += 4) {
    int rrel = (int)rows_s[ri];
    int row = __builtin_amdgcn_readfirstlane(r0 + rrel);
    const float* znr = zn + (size_t)row * D;   // wave-uniform -> scalar loads
    float v[D];
#pragma unroll
    for (int d = 0; d < D; ++d) v[d] = znr[d];

    unsigned long long best = 0ull;
#pragma unroll
    for (int cc = 0; cc < CH / 64; ++cc) {
      int kl = lane + cc * 64;
      float a = -enh_s[kl];
      const float* ep = &en_s[kl * 36];
#pragma unroll
      for (int jj = 0; jj < 8; ++jj) {             // exact k_cleanup fma order
        float4 e = *reinterpret_cast<const float4*>(&ep[jj * 4]);
        a = fmaf(v[4 * jj + 0], e.x, a);
        a = fmaf(v[4 * jj + 1], e.y, a);
        a = fmaf(v[4 * jj + 2], e.z, a);
        a = fmaf(v[4 * jj + 3], e.w, a);
      }
      int k = c * CH + kl;
      unsigned o = __float_as_uint(a);
      o = (o & 0x80000000u) ? ~o : (o | 0x80000000u);
      unsigned long long pk = ((unsigned long long)o << 32) | (unsigned)(8191 - k);
      best = (pk > best) ? pk : best;
    }
#pragma unroll
    for (int m = 32; m >= 1; m >>= 1) {
      unsigned long long op = __shfl_xor(best, m, 64);
      best = (op > best) ? op : best;              // max s, tie -> min k
    }
    if (lane == 0) {
      unsigned uo = (unsigned)(best >> 32);
      unsigned uu = (uo & 0x80000000u) ? (uo & 0x7FFFFFFFu) : ~uo;
      float sC = __uint_as_float(uu);              // winner: dot - 0.5||e||^2
      int kC = 8191 - (int)(unsigned)(best & 0xFFFFFFFFull);
      float dotw = sC + enh_s[kC - c * CH];        // winner's raw dot
      if (row_s2[row] > dotw - MARGIN) {           // another chunk may win
        int pos = atomicAdd(&nflag, 1);
        flg_s[pos] = (unsigned short)rrel;         // exact full-scan below
      } else {
        idx_ws[row] = kC;
      }
    }
  }
  __syncthreads();
  const int nf = nflag;

  // exact full scan for ambiguous rows: whole block, 32 codes/lane/wave
  for (int fi = 0; fi < nf; ++fi) {
    int row = __builtin_amdgcn_readfirstlane(r0 + (int)flg_s[fi]);
    const float* znr = zn + (size_t)row * D;
    float v[D];
#pragma unroll
    for (int d = 0; d < D; ++d) v[d] = znr[d];

    unsigned long long best = 0ull;
#pragma unroll
    for (int cc = 0; cc < 32; ++cc) {
      int k = wid * 2048 + cc * 64 + lane;
      const float4* er = reinterpret_cast<const float4*>(en + (size_t)k * D);
      float a = -en_h[k];
#pragma unroll
      for (int jj = 0; jj < 8; ++jj) {             // bitwise same as old cleanup
        float4 e = er[jj];
        a = fmaf(v[4 * jj + 0], e.x, a);
        a = fmaf(v[4 * jj + 1], e.y, a);
        a = fmaf(v[4 * jj + 2], e.z, a);
        a = fmaf(v[4 * jj + 3], e.w, a);
      }
      unsigned o = __float_as_uint(a);
      o = (o & 0x80000000u) ? ~o : (o | 0x80000000u);
      unsigned long long pk = ((unsigned long long)o << 32) | (unsigned)(8191 - k);
      best = (pk > best) ? pk : best;
    }
#pragma unroll
    for (int m = 32; m >= 1; m >>= 1) {
      unsigned long long op = __shfl_xor(best, m, 64);
      best = (op > best) ? op : best;              // max s, tie -> min k
    }
    if (lane == 0) wred[wid] = best;
    __syncthreads();
    if (tid == 0) {
      unsigned long long m01 = (wred[0] > wred[1]) ? wred[0] : wred[1];
      unsigned long long m23 = (wred[2] > wred[3]) ? wred[2] : wred[3];
      unsigned long long mm = (m01 > m23) ? m01 : m23;
      idx_ws[row] = 8191 - (int)(unsigned)(mm & 0xFFFFFFFFull);
    }
    __syncthreads();                               // protect wred for next row
  }
}

__global__ __launch_bounds__(256) void k_epi(const float* __restrict__ z,
                                             const float* __restrict__ en,
                                             const int* __restrict__ idx_ws,
                                             float* __restrict__ out_z,
                                             float* __restrict__ loss,
                                             float* __restrict__ out_idx,
                                             float scale) {
  int row = blockIdx.x * 256 + threadIdx.x;
  int kb = idx_ws[row];
  out_idx[row] = (float)kb;  // whole out buffer read back as f32

  const float4* p = reinterpret_cast<const float4*>(z + (size_t)row * D);
  float4 q[D / 4];
#pragma unroll
  for (int j = 0; j < D / 4; ++j) q[j] = p[j];
  float ss = 0.f;
#pragma unroll
  for (int j = 0; j < D / 4; ++j)
    ss = fmaf(q[j].x, q[j].x, fmaf(q[j].y, q[j].y, fmaf(q[j].z, q[j].z, fmaf(q[j].w, q[j].w, ss))));
  float n = fmaxf(sqrtf(ss), EPS);

  const float4* ep = reinterpret_cast<const float4*>(en + (size_t)kb * D);
  float4* op = reinterpret_cast<float4*>(out_z + (size_t)row * D);
  float s = 0.f;
#pragma unroll
  for (int j = 0; j < D / 4; ++j) {
    float4 e = ep[j];
    float4 o;
    o.x = q[j].x + (e.x - q[j].x);  // STE forward value, reference op order
    o.y = q[j].y + (e.y - q[j].y);
    o.z = q[j].z + (e.z - q[j].z);
    o.w = q[j].w + (e.w - q[j].w);
    op[j] = o;
    float dx = e.x - q[j].x / n;  float dy = e.y - q[j].y / n;
    float dz = e.z - q[j].z / n;  float dw = e.w - q[j].w / n;
    s = fmaf(dx, dx, fmaf(dy, dy, fmaf(dz, dz, fmaf(dw, dw, s))));
  }

#pragma unroll
  for (int off = 32; off > 0; off >>= 1) s += __shfl_down(s, off, 64);
  __shared__ float wsum[4];
  int lane = threadIdx.x & 63, wid = threadIdx.x >> 6;
  if (lane == 0) wsum[wid] = s;
  __syncthreads();
  if (threadIdx.x == 0) {
    float tt = (wsum[0] + wsum[1]) + (wsum[2] + wsum[3]);
    atomicAdd(loss, tt * scale);
  }
}

extern "C" void kernel_launch(void* const* d_in, const int* in_sizes, int n_in,
                              void* d_out, int out_size, void* d_ws, size_t ws_size,
                              hipStream_t stream) {
  const float* z = (const float*)d_in[0];
  const float* emb = (const float*)d_in[1];
  const int N = in_sizes[0] / D;  // 32768
  const int K = in_sizes[1] / D;  // 8192

  float* out = (float*)d_out;
  float* out_z = out;                        // N*D
  float* loss = out + (size_t)N * D;         // 1
  float* out_idx = out + (size_t)N * D + 1;  // N

  // zn (normalized z, fp32) lives in the out_z region until k_epi overwrites it
  float* zn = out_z;

  // ws layout (~8 MB)
  char* w = (char*)d_ws;
  float* en = (float*)w;                         w += (size_t)K * D * 4;     // 1 MB
  float* en_h = (float*)w;                       w += (size_t)K * 4;         // 32 KB
  unsigned short* eswz = (unsigned short*)w;     w += (size_t)K * D * 2 * 2; // 1 MB
  unsigned short* zswz_hi = (unsigned short*)w;  w += (size_t)N * D * 2;     // 2 MB
  unsigned short* zswz_lo = (unsigned short*)w;  w += (size_t)N * D * 2;     // 2 MB
  int* idx_ws = (int*)w;                         w += (size_t)N * 4;         // 128 KB
  float* res_s1 = (float*)w;                     w += (size_t)N * 4 * 4;     // 512 KB
  int* res_cb = (int*)w;                         w += (size_t)N * 4 * 4;     // 512 KB
  float* res_s2 = (float*)w;                     w += (size_t)N * 4 * 4;     // 512 KB
  int* row_cb = (int*)w;                         w += (size_t)N * 4;         // 128 KB
  float* row_s2 = (float*)w;                     w += (size_t)N * 4;         // 128 KB

  k_prep<<<dim3((K + N) / 256), 256, 0, stream>>>(
      z, emb, en, en_h, eswz, zswz_hi, zswz_lo, zn, loss, N);

  k_argmin_mfma<<<dim3((N / 256) * 4), 256, 0, stream>>>(
      zswz_hi, zswz_lo, eswz, res_s1, res_cb, res_s2);

  k_merge<<<dim3(N / 256), 256, 0, stream>>>(
      res_s1, res_cb, res_s2, row_cb, row_s2);

  k_rescore<<<dim3(NCHUNK * 8), 256, 0, stream>>>(
      zn, en, en_h, row_cb, row_s2, idx_ws, N);

  k_epi<<<dim3(N / 256), 256, 0, stream>>>(
      z, en, idx_ws, out_z, loss, out_idx, 1.25f / (float)((size_t)N * D));
}

// Round 7
// 170.023 us; speedup vs baseline: 2.6174x; 2.6174x over previous
//
#include <hip/hip_runtime.h>
#include <math.h>

// ViT Vector Quantizer: z [32,1024,32] f32, embedding [8192,32] f32.
// Outputs (concat, read as f32): z_q_out [N*D], loss [1], idx [N] (as floats).
//
// R12b: resubmit of R12 (container-acquisition failure, no kernel verdict).
// R10 structure (172.8 us verified) with ONE change:
//   - k_argmin_mfma: 128-code staging chunks (2x16KB LDS dbuf, was 2x32KB) +
//     __launch_bounds__(256,4) -> 4 blocks/CU (was 2). m114: resident blocks
//     overlap each other's barrier/DMA drains -> MfmaUtil 46% -> ~60%.
//     Chunk IDs still recorded at 256-code granularity ((qt*16+c)>>1) so all
//     downstream kernels (merge/rescore/cleanup) are bit-identical to R10;
//     s2 is slightly conservative (sibling 128-half counts) -> safe direction.
//   K0 k_prep -> K1 k_argmin_mfma -> K1b k_merge -> K2 k_rescore
//   -> K3 k_cleanup -> K4 k_epi.

#define D 32
#define KCODES 8192
#define MARGIN 2.5e-4f     // ~20x worst-case split-bf16 error bound
#define EPS 1e-12f

typedef short bf16x8 __attribute__((ext_vector_type(8)));
typedef unsigned short u16x8 __attribute__((ext_vector_type(8)));
typedef float f32x4 __attribute__((ext_vector_type(4)));

static __device__ __forceinline__ unsigned short f2bf(float x) {  // RNE bf16 bits
  unsigned u = __float_as_uint(x);
  return (unsigned short)((u + 0x7FFFu + ((u >> 16) & 1u)) >> 16);
}
static __device__ __forceinline__ float bf2f(unsigned short s) {
  return __uint_as_float(((unsigned)s) << 16);
}
static __device__ __forceinline__ void gload_lds16(const void* g, void* l) {
  __builtin_amdgcn_global_load_lds(
      (const __attribute__((address_space(1))) void*)g,
      (__attribute__((address_space(3))) void*)l, 16, 0, 0);
}

// MFMA fragment layouts (validated in prior rounds; A and B mappings are
// identical index formulas, so the same swizzled data serves either operand):
//   A[m][k]: m = lane&15, k = (lane>>4)*8 + j   (8 bf16/lane, contiguous 16B)
//   B[k][n]: n = lane&15, k = (lane>>4)*8 + j
//   C[m][n]: n = lane&15, m = (lane>>4)*4 + reg

__global__ __launch_bounds__(256) void k_prep(const float* __restrict__ z,
                                              const float* __restrict__ emb,
                                              float* __restrict__ en,
                                              float* __restrict__ en_h,
                                              unsigned short* __restrict__ eswz,
                                              unsigned short* __restrict__ zswz_hi,
                                              unsigned short* __restrict__ zswz_lo,
                                              float* __restrict__ zn,
                                              int* __restrict__ cnt,
                                              float* __restrict__ loss,
                                              unsigned long long* __restrict__ mp2,
                                              int N) {
  int v = blockIdx.x * 256 + threadIdx.x;
  if (v == 0) { *cnt = 0; *loss = 0.f; }
  if (v >= KCODES + N) return;
  if (v >= KCODES) mp2[v - KCODES] = 0ull;   // atomicMax identity
  const float* src = (v < KCODES) ? (emb + (size_t)v * D) : (z + (size_t)(v - KCODES) * D);

  float x[D];
  const float4* p = reinterpret_cast<const float4*>(src);
#pragma unroll
  for (int j = 0; j < D / 4; ++j) {
    float4 q = p[j];
    x[4 * j + 0] = q.x; x[4 * j + 1] = q.y; x[4 * j + 2] = q.z; x[4 * j + 3] = q.w;
  }
  float ss = 0.f;
#pragma unroll
  for (int j = 0; j < D; ++j) ss = fmaf(x[j], x[j], ss);
  float n = fmaxf(sqrtf(ss), EPS);
#pragma unroll
  for (int j = 0; j < D; ++j) x[j] = x[j] / n;   // true division mirrors reference

  unsigned short hi[D], lo[D];
#pragma unroll
  for (int j = 0; j < D; ++j) {
    hi[j] = f2bf(x[j]);
    lo[j] = f2bf(x[j] - bf2f(hi[j]));   // x - bf16(x) exact in fp32
  }

  if (v < KCODES) {
    float4* o = reinterpret_cast<float4*>(en + (size_t)v * D);
    float s2 = 0.f;
#pragma unroll
    for (int j = 0; j < D / 4; ++j) {
      float4 q = {x[4 * j], x[4 * j + 1], x[4 * j + 2], x[4 * j + 3]};
      s2 = fmaf(q.x, q.x, fmaf(q.y, q.y, fmaf(q.z, q.z, fmaf(q.w, q.w, s2))));
      o[j] = q;
    }
    en_h[v] = 0.5f * s2;
    int tl = v >> 4, m = v & 15;    // fragment swizzle (tile-of-16 codes)
#pragma unroll
    for (int q = 0; q < 4; ++q) {
      u16x8 hv, lv;
#pragma unroll
      for (int j = 0; j < 8; ++j) { hv[j] = hi[8 * q + j]; lv[j] = lo[8 * q + j]; }
      *(u16x8*)(eswz + (size_t)tl * 1024 + (q * 16 + m) * 8) = hv;
      *(u16x8*)(eswz + (size_t)tl * 1024 + 512 + (q * 16 + m) * 8) = lv;
    }
  } else {
    int r = v - KCODES;
    float4* zo = reinterpret_cast<float4*>(zn + (size_t)r * D);
#pragma unroll
    for (int j = 0; j < D / 4; ++j) {   // bitwise-exact normalized z for
      float4 q = {x[4 * j], x[4 * j + 1], x[4 * j + 2], x[4 * j + 3]};
      zo[j] = q;                        // k_rescore / k_cleanup
    }
    int g = r >> 4, m = r & 15;     // fragment swizzle (group-of-16 rows)
#pragma unroll
    for (int q = 0; q < 4; ++q) {
      u16x8 hv, lv;
#pragma unroll
      for (int j = 0; j < 8; ++j) { hv[j] = hi[8 * q + j]; lv[j] = lo[8 * q + j]; }
      *(u16x8*)(zswz_hi + (size_t)g * 512 + (q * 16 + m) * 8) = hv;
      *(u16x8*)(zswz_lo + (size_t)g * 512 + (q * 16 + m) * 8) = lv;
    }
  }
}

// Deferred-argmax MFMA pass. Grid = (N/256) row-sets x 4 code-quarters.
// Block = 4 waves; each wave holds z-fragments for 4 row-groups (64 rows) so
// one A-fragment (codes) LDS read feeds 12 MFMAs. 128-code chunks double-
// buffered in 2x16KB LDS + launch_bounds(256,4) -> 4 blocks/CU so resident
// blocks overlap each other's barrier/DMA drains (m114). Chunk-best recorded
// at 256-code granularity for downstream compatibility.
__global__ __launch_bounds__(256, 4) void k_argmin_mfma(
    const unsigned short* __restrict__ zswz_hi,
    const unsigned short* __restrict__ zswz_lo,
    const unsigned short* __restrict__ eswz,
    float* __restrict__ res_s1, int* __restrict__ res_cb,
    float* __restrict__ res_s2) {
  __shared__ unsigned short lds_sh[2][8192];    // 2 x 16 KB double buffer

  const int tid = threadIdx.x;
  const int wid = tid >> 6, lane = tid & 63;
  const int lane15 = lane & 15, quad = lane >> 4;
  const int rs = blockIdx.x >> 2;               // row-set (256 rows)
  const int qt = blockIdx.x & 3;                // code quarter (16 x 128-chunks)

  bf16x8 zhi[4], zlo[4];
#pragma unroll
  for (int rg = 0; rg < 4; ++rg) {
    int g = rs * 16 + wid * 4 + rg;
    zhi[rg] = *(const bf16x8*)(zswz_hi + (size_t)g * 512 + lane * 8);
    zlo[rg] = *(const bf16x8*)(zswz_lo + (size_t)g * 512 + lane * 8);
  }

  float cm[4], s1g[4], s2c[4];
  int cb[4];
#pragma unroll
  for (int rg = 0; rg < 4; ++rg) {
    cm[rg] = -3.4e38f; s1g[rg] = -3.4e38f; s2c[rg] = -3.4e38f; cb[rg] = 0;
  }
  const f32x4 zero4 = {0.f, 0.f, 0.f, 0.f};

  // chunk = 128 codes = 8 tiles = 16 KB = 1024 float4; 4 x 16B per thread
  const float4* gall = reinterpret_cast<const float4*>(eswz) + (size_t)qt * 16 * 1024;
#pragma unroll
  for (int i = 0; i < 4; ++i) {   // stage chunk 0 into buf 0
    int off = i * 256 + tid;      // wave-uniform base + lane-contiguous (m104)
    gload_lds16(gall + off, (char*)&lds_sh[0][0] + (size_t)off * 16);
  }

  for (int c = 0; c < 16; ++c) {
    __syncthreads();              // drains vmcnt -> buffer c&1 fully staged
    if (c + 1 < 16) {             // next DMA overlaps this chunk's compute
      const float4* gn = gall + (size_t)(c + 1) * 1024;
      char* dst = (char*)&lds_sh[(c + 1) & 1][0];
#pragma unroll
      for (int i = 0; i < 4; ++i) {
        int off = i * 256 + tid;
        gload_lds16(gn + off, dst + (size_t)off * 16);
      }
    }
    const unsigned short* buf = &lds_sh[c & 1][0];
#pragma unroll
    for (int t = 0; t < 8; ++t) {
      bf16x8 ahi = *(const bf16x8*)(buf + t * 1024 + lane * 8);
      bf16x8 alo = *(const bf16x8*)(buf + t * 1024 + 512 + lane * 8);
#pragma unroll
      for (int rg = 0; rg < 4; ++rg) {
        // A = codes, B = z: C[m][n] -> n=lane15 = row-in-group, m = code
        f32x4 acc = __builtin_amdgcn_mfma_f32_16x16x32_bf16(ahi, zhi[rg], zero4, 0, 0, 0);
        acc = __builtin_amdgcn_mfma_f32_16x16x32_bf16(ahi, zlo[rg], acc, 0, 0, 0);
        acc = __builtin_amdgcn_mfma_f32_16x16x32_bf16(alo, zhi[rg], acc, 0, 0, 0);
        cm[rg] = fmaxf(cm[rg],
                       fmaxf(fmaxf(acc[0], acc[1]), fmaxf(acc[2], acc[3])));
      }
    }
    // chunk end: fold 128-chunk max into (s1, best 256-chunk, 2nd-best-partial)
#pragma unroll
    for (int rg = 0; rg < 4; ++rg) {
      float old1 = s1g[rg];
      s2c[rg] = fmaxf(s2c[rg], fminf(cm[rg], old1));
      bool better = cm[rg] > old1;                // strict: earlier chunk on tie
      cb[rg] = better ? ((qt * 16 + c) >> 1) : cb[rg];   // 256-code chunk id
      s1g[rg] = better ? cm[rg] : old1;
      cm[rg] = -3.4e38f;
    }
  }

  // merge the 4 quads (disjoint code subsets of same rows): xor 16 then 32
#pragma unroll
  for (int m = 16; m <= 32; m <<= 1) {
#pragma unroll
    for (int rg = 0; rg < 4; ++rg) {
      float o1 = __shfl_xor(s1g[rg], m, 64);
      float o2 = __shfl_xor(s2c[rg], m, 64);
      int ob = __shfl_xor(cb[rg], m, 64);
      s2c[rg] = fmaxf(fmaxf(s2c[rg], o2), fminf(s1g[rg], o1));
      bool better = o1 > s1g[rg];
      s1g[rg] = better ? o1 : s1g[rg];
      cb[rg] = better ? ob : cb[rg];
    }
  }
  if (quad == 0) {
#pragma unroll
    for (int rg = 0; rg < 4; ++rg) {
      int row = rs * 256 + wid * 64 + rg * 16 + lane15;
      res_s1[(size_t)row * 4 + qt] = s1g[rg];
      res_cb[(size_t)row * 4 + qt] = cb[rg];
      res_s2[(size_t)row * 4 + qt] = s2c[rg];
    }
  }
}

// Per-row merge of the 4 code-quarter results. float4/int4 coalesced.
__global__ __launch_bounds__(256) void k_merge(const float* __restrict__ res_s1,
                                               const int* __restrict__ res_cb,
                                               const float* __restrict__ res_s2,
                                               int* __restrict__ row_cb,
                                               float* __restrict__ row_s2) {
  int row = blockIdx.x * 256 + threadIdx.x;
  float4 s1q = reinterpret_cast<const float4*>(res_s1)[row];
  float4 s2q = reinterpret_cast<const float4*>(res_s2)[row];
  int4 cbq = reinterpret_cast<const int4*>(res_cb)[row];
  float s1b = s1q.x;  int cbb = cbq.x;  float s2b = s2q.x;
  {
    float s1p = s1q.y, s2p = s2q.y; int cbp = cbq.y;
    s2b = fmaxf(fmaxf(s2b, s2p), fminf(s1b, s1p));
    bool better = s1p > s1b;  s1b = better ? s1p : s1b;  cbb = better ? cbp : cbb;
  }
  {
    float s1p = s1q.z, s2p = s2q.z; int cbp = cbq.z;
    s2b = fmaxf(fmaxf(s2b, s2p), fminf(s1b, s1p));
    bool better = s1p > s1b;  s1b = better ? s1p : s1b;  cbb = better ? cbp : cbb;
  }
  {
    float s1p = s1q.w, s2p = s2q.w; int cbp = cbq.w;
    s2b = fmaxf(fmaxf(s2b, s2p), fminf(s1b, s1p));
    bool better = s1p > s1b;  s1b = better ? s1p : s1b;  cbb = better ? cbp : cbb;
  }
  row_cb[row] = cbb;
  row_s2[row] = s2b;
}

// Exact fp32 rescore of each row's winning 256-code chunk.
// Grid = 32 chunks x 16 row-ranges. Block stages its chunk (fp32, padded
// stride 36), scans its 2048-row range (4 B/row: pre-merged row_cb), collects
// matching rows (ushort), then row-per-wave: zn scalar loads (no renormalize),
// 4 codes/lane, packed u64 wave argmax (max s, tie -> min k). Flag test:
// s2 (raw approx dot, from row_s2) vs dotw = sC + en_h[kC] (raw exact dot).
__global__ __launch_bounds__(256) void k_rescore(
    const float* __restrict__ zn, const float* __restrict__ en,
    const float* __restrict__ en_h,
    const int* __restrict__ row_cb, const float* __restrict__ row_s2,
    int* __restrict__ idx_ws, int* __restrict__ list, int* __restrict__ cnt,
    int N) {
  __shared__ float en_s[256 * 36];     // [code][36] padded, 16B-aligned rows
  __shared__ float enh_s[256];
  __shared__ unsigned short rows_s[2048];
  __shared__ int nmatch;

  const int tid = threadIdx.x;
  const int c = blockIdx.x >> 4;       // chunk 0..31
  const int sb = blockIdx.x & 15;      // row sub-range
  const int rows_per = N >> 4;         // 2048
  const int r0 = sb * rows_per;

  if (tid == 0) nmatch = 0;
  // stage chunk: 2048 float4 of en -> padded LDS
  const float4* e4 = reinterpret_cast<const float4*>(en) + (size_t)c * 2048;
#pragma unroll
  for (int i = 0; i < 8; ++i) {
    int idx = i * 256 + tid;
    float4 v4 = e4[idx];
    int code = idx >> 3, j = idx & 7;
    *reinterpret_cast<float4*>(&en_s[code * 36 + j * 4]) = v4;
  }
  enh_s[tid] = en_h[c * 256 + tid];
  __syncthreads();

  // scan rows: collect rows whose (pre-merged) best chunk == c
  for (int i = 0; i < rows_per / 256; ++i) {
    int rrel = i * 256 + tid;
    if (row_cb[r0 + rrel] == c) {
      int pos = atomicAdd(&nmatch, 1);
      rows_s[pos] = (unsigned short)rrel;
    }
  }
  __syncthreads();
  const int nm = nmatch;
  const int lane = tid & 63, wid = tid >> 6;

  for (int ri = wid; ri < nm; ri += 4) {
    int row = __builtin_amdgcn_readfirstlane(r0 + (int)rows_s[ri]);
    const float* znr = zn + (size_t)row * D;   // wave-uniform -> scalar loads
    float v[D];
#pragma unroll
    for (int d = 0; d < D; ++d) v[d] = znr[d];  // bitwise same as old normalize

    unsigned long long best = 0ull;
#pragma unroll
    for (int cc = 0; cc < 4; ++cc) {
      int kl = lane + cc * 64;
      float a = -enh_s[kl];
      const float* ep = &en_s[kl * 36];
#pragma unroll
      for (int jj = 0; jj < 8; ++jj) {             // exact k_cleanup fma order
        float4 e = *reinterpret_cast<const float4*>(&ep[jj * 4]);
        a = fmaf(v[4 * jj + 0], e.x, a);
        a = fmaf(v[4 * jj + 1], e.y, a);
        a = fmaf(v[4 * jj + 2], e.z, a);
        a = fmaf(v[4 * jj + 3], e.w, a);
      }
      int k = c * 256 + kl;
      unsigned o = __float_as_uint(a);
      o = (o & 0x80000000u) ? ~o : (o | 0x80000000u);
      unsigned long long pk = ((unsigned long long)o << 32) | (unsigned)(8191 - k);
      best = (pk > best) ? pk : best;
    }
#pragma unroll
    for (int m = 32; m >= 1; m >>= 1) {
      unsigned long long op = __shfl_xor(best, m, 64);
      best = (op > best) ? op : best;              // max s, tie -> min k
    }
    if (lane == 0) {
      unsigned uo = (unsigned)(best >> 32);
      unsigned uu = (uo & 0x80000000u) ? (uo & 0x7FFFFFFFu) : ~uo;
      float sC = __uint_as_float(uu);              // winner: dot - 0.5||e||^2
      int kC = 8191 - (int)(unsigned)(best & 0xFFFFFFFFull);
      float dotw = sC + enh_s[kC - c * 256];       // winner's raw dot
      if (row_s2[row] > dotw - MARGIN) {           // another chunk may win
        int pos = atomicAdd(cnt, 1);
        list[pos] = row;
        idx_ws[row] = -(pos + 1);                  // sentinel: resolved via mp2
      } else {
        idx_ws[row] = kC;
      }
    }
  }
}

// Exact fp32 rescore, THREAD-PER-CODE: task j = (flag i, k-chunk kc); each of the
// 256 threads scores one code; block-reduce; one atomicMax(mp2[i]) per block.
__global__ __launch_bounds__(256) void k_cleanup(const float* __restrict__ zn,
                                                 const float* __restrict__ en,
                                                 const float* __restrict__ en_h,
                                                 const int* __restrict__ list,
                                                 const int* __restrict__ cnt,
                                                 unsigned long long* __restrict__ mp2) {
  __shared__ unsigned long long wred[4];
  const int tid = threadIdx.x;
  const int lane = tid & 63, wid = tid >> 6;
  const int ntask = (*cnt) * 32;               // 32 chunks of 256 codes per row

  for (int j = blockIdx.x; j < ntask; j += gridDim.x) {
    int i = j >> 5, kc = j & 31;
    int row = list[i];
    const float* znr = zn + (size_t)row * D;   // wave-uniform -> scalar loads
    float v[D];
#pragma unroll
    for (int d = 0; d < D; ++d) v[d] = znr[d]; // bitwise same as old normalize

    int k = kc * 256 + tid;                    // contiguous rows -> coalesced
    const float4* er = reinterpret_cast<const float4*>(en + (size_t)k * D);
    float a = -en_h[k];
#pragma unroll
    for (int jj = 0; jj < 8; ++jj) {           // exact R4 fma order
      float4 e = er[jj];
      a = fmaf(v[4 * jj + 0], e.x, a);
      a = fmaf(v[4 * jj + 1], e.y, a);
      a = fmaf(v[4 * jj + 2], e.z, a);
      a = fmaf(v[4 * jj + 3], e.w, a);
    }
    unsigned o = __float_as_uint(a);
    o = (o & 0x80000000u) ? ~o : (o | 0x80000000u);
    unsigned long long pk = ((unsigned long long)o << 32) | (unsigned)(8191 - k);
#pragma unroll
    for (int m = 32; m >= 1; m >>= 1) {
      unsigned long long op = __shfl_xor(pk, m, 64);
      pk = (op > pk) ? op : pk;                // max s, tie -> min k
    }
    if (lane == 0) wred[wid] = pk;
    __syncthreads();
    if (tid == 0) {
      unsigned long long m01 = (wred[0] > wred[1]) ? wred[0] : wred[1];
      unsigned long long m23 = (wred[2] > wred[3]) ? wred[2] : wred[3];
      atomicMax(&mp2[i], (m01 > m23) ? m01 : m23);
    }
    __syncthreads();                           // protect wred for next task
  }
}

__global__ __launch_bounds__(256) void k_epi(const float* __restrict__ z,
                                             const float* __restrict__ en,
                                             const int* __restrict__ idx_ws,
                                             const unsigned long long* __restrict__ mp2,
                                             float* __restrict__ out_z,
                                             float* __restrict__ loss,
                                             float* __restrict__ out_idx,
                                             float scale) {
  int row = blockIdx.x * 256 + threadIdx.x;
  int kb = idx_ws[row];
  if (kb < 0) {                                // flagged: exact result in mp2
    unsigned long long m = mp2[-kb - 1];
    kb = 8191 - (int)(unsigned)(m & 0xFFFFFFFFull);
  }
  out_idx[row] = (float)kb;  // whole out buffer read back as f32

  const float4* p = reinterpret_cast<const float4*>(z + (size_t)row * D);
  float4 q[D / 4];
#pragma unroll
  for (int j = 0; j < D / 4; ++j) q[j] = p[j];
  float ss = 0.f;
#pragma unroll
  for (int j = 0; j < D / 4; ++j)
    ss = fmaf(q[j].x, q[j].x, fmaf(q[j].y, q[j].y, fmaf(q[j].z, q[j].z, fmaf(q[j].w, q[j].w, ss))));
  float n = fmaxf(sqrtf(ss), EPS);

  const float4* ep = reinterpret_cast<const float4*>(en + (size_t)kb * D);
  float4* op = reinterpret_cast<float4*>(out_z + (size_t)row * D);
  float s = 0.f;
#pragma unroll
  for (int j = 0; j < D / 4; ++j) {
    float4 e = ep[j];
    float4 o;
    o.x = q[j].x + (e.x - q[j].x);  // STE forward value, reference op order
    o.y = q[j].y + (e.y - q[j].y);
    o.z = q[j].z + (e.z - q[j].z);
    o.w = q[j].w + (e.w - q[j].w);
    op[j] = o;
    float dx = e.x - q[j].x / n;  float dy = e.y - q[j].y / n;
    float dz = e.z - q[j].z / n;  float dw = e.w - q[j].w / n;
    s = fmaf(dx, dx, fmaf(dy, dy, fmaf(dz, dz, fmaf(dw, dw, s))));
  }

#pragma unroll
  for (int off = 32; off > 0; off >>= 1) s += __shfl_down(s, off, 64);
  __shared__ float wsum[4];
  int lane = threadIdx.x & 63, wid = threadIdx.x >> 6;
  if (lane == 0) wsum[wid] = s;
  __syncthreads();
  if (threadIdx.x == 0) {
    float tt = (wsum[0] + wsum[1]) + (wsum[2] + wsum[3]);
    atomicAdd(loss, tt * scale);
  }
}

extern "C" void kernel_launch(void* const* d_in, const int* in_sizes, int n_in,
                              void* d_out, int out_size, void* d_ws, size_t ws_size,
                              hipStream_t stream) {
  const float* z = (const float*)d_in[0];
  const float* emb = (const float*)d_in[1];
  const int N = in_sizes[0] / D;  // 32768
  const int K = in_sizes[1] / D;  // 8192

  float* out = (float*)d_out;
  float* out_z = out;                        // N*D
  float* loss = out + (size_t)N * D;         // 1
  float* out_idx = out + (size_t)N * D + 1;  // N

  // zn (normalized z, fp32) lives in the out_z region until k_epi overwrites it
  float* zn = out_z;

  // ws layout (~8.5 MB)
  char* w = (char*)d_ws;
  float* en = (float*)w;                         w += (size_t)K * D * 4;     // 1 MB
  float* en_h = (float*)w;                       w += (size_t)K * 4;         // 32 KB
  unsigned short* eswz = (unsigned short*)w;     w += (size_t)K * D * 2 * 2; // 1 MB
  unsigned short* zswz_hi = (unsigned short*)w;  w += (size_t)N * D * 2;     // 2 MB
  unsigned short* zswz_lo = (unsigned short*)w;  w += (size_t)N * D * 2;     // 2 MB
  int* idx_ws = (int*)w;                         w += (size_t)N * 4;         // 128 KB
  int* list = (int*)w;                           w += (size_t)N * 4;         // 128 KB
  unsigned long long* mp2 = (unsigned long long*)w; w += (size_t)N * 8;      // 256 KB
  float* res_s1 = (float*)w;                     w += (size_t)N * 4 * 4;     // 512 KB
  int* res_cb = (int*)w;                         w += (size_t)N * 4 * 4;     // 512 KB
  float* res_s2 = (float*)w;                     w += (size_t)N * 4 * 4;     // 512 KB
  int* row_cb = (int*)w;                         w += (size_t)N * 4;         // 128 KB
  float* row_s2 = (float*)w;                     w += (size_t)N * 4;         // 128 KB
  int* cnt = (int*)w;

  k_prep<<<dim3((K + N) / 256), 256, 0, stream>>>(
      z, emb, en, en_h, eswz, zswz_hi, zswz_lo, zn, cnt, loss, mp2, N);

  k_argmin_mfma<<<dim3((N / 256) * 4), 256, 0, stream>>>(
      zswz_hi, zswz_lo, eswz, res_s1, res_cb, res_s2);

  k_merge<<<dim3(N / 256), 256, 0, stream>>>(
      res_s1, res_cb, res_s2, row_cb, row_s2);

  k_rescore<<<dim3(32 * 16), 256, 0, stream>>>(
      zn, en, en_h, row_cb, row_s2, idx_ws, list, cnt, N);

  k_cleanup<<<dim3(4096), 256, 0, stream>>>(zn, en, en_h, list, cnt, mp2);

  k_epi<<<dim3(N / 256), 256, 0, stream>>>(
      z, en, idx_ws, mp2, out_z, loss, out_idx, 1.25f / (float)((size_t)N * D));
}